// Round 13
// baseline (218.096 us; speedup 1.0000x reference)
//
#include <hip/hip_runtime.h>
#include <hip/hip_bf16.h>
#include <cstdint>
#include <cstddef>

// ---------------------------------------------------------------------------
// CausalSelfAttention fused block, MI355X/gfx950.  Round 13:
//  - attn: flash-decoding split for qt>=16 (2 jobs/block-row, <=16 KV tiles
//    per job, partial (o,m,l) + combine kernel) -> serial critical path
//    halves (R12 was pinned by the 32-tile qt=31 blocks).
//  - softmax: rsum lane-reduction deferred out of the tile loop (-16 shfl/tile).
//  - everything else unchanged from R12.
// B=2 T=2048 D=2048 NH=16 NKV=4 HD=128 ROPE=64.
// ---------------------------------------------------------------------------

typedef _Float16 f16_t;
typedef f16_t f16x8 __attribute__((ext_vector_type(8)));
typedef float f32x4 __attribute__((ext_vector_type(4)));

#define MFMA16F(a, b, c) __builtin_amdgcn_mfma_f32_16x16x32_f16((a), (b), (c), 0, 0, 0)
#define SBAR()   __builtin_amdgcn_s_barrier()
#define SCHED0() __builtin_amdgcn_sched_barrier(0)
#define LGKM0()  asm volatile("s_waitcnt lgkmcnt(0)" ::: "memory")

__device__ __forceinline__ void gload16(const f16_t* g, f16_t* l) {
  auto lds_ptr = reinterpret_cast<__attribute__((address_space(3))) unsigned int*>(
      reinterpret_cast<uintptr_t>(l));
  auto g_ptr = reinterpret_cast<const __attribute__((address_space(1))) unsigned int*>(
      reinterpret_cast<uintptr_t>(g));
  __builtin_amdgcn_global_load_lds(g_ptr, lds_ptr, 16, 0, 0);
}

// ---------------------------------------------------------------------------
// fp32 -> fp16 cast, vectorized
// ---------------------------------------------------------------------------
__global__ void k_cast_f16(const float* __restrict__ in, f16_t* __restrict__ o, long n) {
  long i = ((long)blockIdx.x * blockDim.x + threadIdx.x) * 4;
  const long step = (long)gridDim.x * blockDim.x * 4;
  for (; i < n; i += step) {
    const float4 v = *reinterpret_cast<const float4*>(in + i);
    f16_t r[4] = {(f16_t)v.x, (f16_t)v.y, (f16_t)v.z, (f16_t)v.w};
    *reinterpret_cast<uint64_t*>(o + i) = *reinterpret_cast<const uint64_t*>(r);
  }
}

// ---------------------------------------------------------------------------
// merged W cast: rows 0-2047 Wq, 2048-2559 Wk, 2560-3071 Wv -> wf [3072][2048]
// ---------------------------------------------------------------------------
__global__ void k_cast_wqkv(const float* __restrict__ Wq, const float* __restrict__ Wk,
                            const float* __restrict__ Wv, f16_t* __restrict__ wf) {
  long i = ((long)blockIdx.x * blockDim.x + threadIdx.x) * 4;
  const long step = (long)gridDim.x * blockDim.x * 4;
  for (; i < (long)3072 * 2048; i += step) {
    const long row = i >> 11, col = i & 2047;
    const float* src = (row < 2048) ? (Wq + (size_t)row * 2048)
                     : (row < 2560) ? (Wk + (size_t)(row - 2048) * 2048)
                                    : (Wv + (size_t)(row - 2560) * 2048);
    const float4 v = *reinterpret_cast<const float4*>(src + col);
    f16_t r[4] = {(f16_t)v.x, (f16_t)v.y, (f16_t)v.z, (f16_t)v.w};
    *reinterpret_cast<uint64_t*>(wf + row * 2048 + col) = *reinterpret_cast<const uint64_t*>(r);
  }
}

// ---------------------------------------------------------------------------
// RoPE cos/sin table: [T=2048][32]
// ---------------------------------------------------------------------------
__global__ void k_rope_tab(float* __restrict__ ctab, float* __restrict__ stab) {
  const int idx = blockIdx.x * blockDim.x + threadIdx.x;
  if (idx >= 2048 * 32) return;
  const int t = idx >> 5, i = idx & 31;
  const float freq = exp2f(-(float)i * 0.2076205059304601f);  // 10000^(-i/64)
  const float f = (float)t * freq;
  ctab[idx] = cosf(f);
  stab[idx] = sinf(f);
}

// ---------------------------------------------------------------------------
// V transpose: vn [bk][2048 t][128 d] -> vt [bk][128 d][2048 t].
// ---------------------------------------------------------------------------
__global__ __launch_bounds__(256) void k_vtrans(
    const f16_t* __restrict__ vn, f16_t* __restrict__ vt)
{
  __shared__ __align__(16) f16_t lsT[64 * 136];
  const int t0 = blockIdx.x * 64;
  const int bk = blockIdx.y;
  const f16_t* src = vn + ((size_t)bk * 2048 + t0) * 128;
  f16_t* dst = vt + (size_t)bk * 128 * 2048;
  const int tid = threadIdx.x;
#pragma unroll
  for (int it = 0; it < 4; ++it) {
    const int cch = tid + it * 256;
    const int r = cch >> 4, c = cch & 15;
    *reinterpret_cast<f16x8*>(&lsT[r * 136 + c * 8]) =
        *reinterpret_cast<const f16x8*>(src + (size_t)r * 128 + c * 8);
  }
  __syncthreads();
#pragma unroll
  for (int it = 0; it < 4; ++it) {
    const int u = tid + it * 256;
    const int d = u >> 3, c8 = u & 7;
    f16_t vals[8];
#pragma unroll
    for (int j = 0; j < 8; ++j) vals[j] = lsT[(c8 * 8 + j) * 136 + d];
    *reinterpret_cast<f16x8*>(dst + (size_t)d * 2048 + t0 + c8 * 8) =
        *reinterpret_cast<const f16x8*>(vals);
  }
}

// ---------------------------------------------------------------------------
// 256 x (64*NBU) NT GEMM, fp16 in, OutT out (R10/R11 proven).
// 1024 threads = 16 waves (4M x 4N); BK=64; 2-phase counted-vmcnt.
// ---------------------------------------------------------------------------
template <int NBU, typename OutT>
__global__ __launch_bounds__(1024, 1) void k_gemmQ(
    const f16_t* __restrict__ A, const f16_t* __restrict__ Bm,
    OutT* __restrict__ C, int M, int N, int K, int lda, int ldb)
{
  __shared__ __align__(16) f16_t lds[2][(4 + NBU) * 4096];
  const int tid = threadIdx.x;
  const int l = tid & 63, w = tid >> 6;       // w 0..15
  const int lrow = l & 15, lk = l >> 4;
  const int wm = w >> 2, wn = w & 3;          // 4 x 4 wave grid

  const int nwg = gridDim.x * gridDim.y;
  int lin = blockIdx.y * gridDim.x + blockIdx.x;
  lin = (lin & 7) * (nwg >> 3) + (lin >> 3);
  const int m0 = (lin / gridDim.x) * 256, n0 = (lin % gridDim.x) * (64 * NBU);

  const bool stager = (tid < 512);
  const int srow = tid >> 3;
  const int scol = ((tid & 7) ^ (srow & 7)) << 3;
  const f16_t* gP[4 + NBU];
#pragma unroll
  for (int u = 0; u < 4; ++u) gP[u] = A + (size_t)(m0 + u * 64 + srow) * lda + scol;
#pragma unroll
  for (int u = 0; u < NBU; ++u) gP[4 + u] = Bm + (size_t)(n0 + u * 64 + srow) * ldb + scol;

  auto stageAll = [&](int buf, int k0) {
#pragma unroll
    for (int u = 0; u < 4 + NBU; ++u)
      gload16(gP[u] + k0, &lds[buf][u * 4096 + tid * 8]);
  };
  auto rdA = [&](int buf, int mf, int ks) -> f16x8 {
    const int row = wm * 64 + mf * 16 + lrow;             // 0..255
    const int slot = ((ks << 2) | lk) ^ (row & 7);
    return *reinterpret_cast<const f16x8*>(&lds[buf][row * 64 + slot * 8]);
  };
  auto rdB = [&](int buf, int nf, int ks) -> f16x8 {
    const int row = wn * (16 * NBU) + nf * 16 + lrow;     // 0..64*NBU-1
    const int slot = ((ks << 2) | lk) ^ (row & 7);
    return *reinterpret_cast<const f16x8*>(&lds[buf][16384 + row * 64 + slot * 8]);
  };

  f32x4 acc[4][NBU] = {};
  const int nkt = K >> 6;

  if (stager) {
    stageAll(0, 0);
    stageAll(1, nkt > 1 ? 64 : 0);
  }
  if constexpr (NBU == 3) { asm volatile("s_waitcnt vmcnt(7)" ::: "memory"); }
  else                    { asm volatile("s_waitcnt vmcnt(6)" ::: "memory"); }
  SCHED0();
  SBAR(); SCHED0();

  f16x8 aA[4][2], bB[NBU][2];
  for (int kt = 0; kt < nkt; ++kt) {
    const int b = kt & 1;
    const int kn2 = (kt + 2 < nkt ? kt + 2 : nkt - 1) << 6;

    // phase 1: read all frags of tile t, MFMA mf 0..1
#pragma unroll
    for (int mf = 0; mf < 4; ++mf) { aA[mf][0] = rdA(b, mf, 0); aA[mf][1] = rdA(b, mf, 1); }
#pragma unroll
    for (int nf = 0; nf < NBU; ++nf) { bB[nf][0] = rdB(b, nf, 0); bB[nf][1] = rdB(b, nf, 1); }
    __builtin_amdgcn_s_setprio(1);
#pragma unroll
    for (int mf = 0; mf < 2; ++mf)
#pragma unroll
      for (int nf = 0; nf < NBU; ++nf)
#pragma unroll
        for (int ks = 0; ks < 2; ++ks)
          acc[mf][nf] = MFMA16F(aA[mf][ks], bB[nf][ks], acc[mf][nf]);
    __builtin_amdgcn_s_setprio(0);
    LGKM0(); SCHED0();
    SBAR(); SCHED0();

    // phase 2: stage tile t+2 over dead buf b; wait tile t+1; MFMA mf 2..3
    if (stager) stageAll(b, kn2);
    if constexpr (NBU == 3) { asm volatile("s_waitcnt vmcnt(7)" ::: "memory"); }
    else                    { asm volatile("s_waitcnt vmcnt(6)" ::: "memory"); }
    SCHED0();
    __builtin_amdgcn_s_setprio(1);
#pragma unroll
    for (int mf = 2; mf < 4; ++mf)
#pragma unroll
      for (int nf = 0; nf < NBU; ++nf)
#pragma unroll
        for (int ks = 0; ks < 2; ++ks)
          acc[mf][nf] = MFMA16F(aA[mf][ks], bB[nf][ks], acc[mf][nf]);
    __builtin_amdgcn_s_setprio(0);
    SBAR(); SCHED0();
  }

  // C-write
#pragma unroll
  for (int mf = 0; mf < 4; ++mf) {
    const int row = m0 + wm * 64 + mf * 16 + lk * 4;
#pragma unroll
    for (int nf = 0; nf < NBU; ++nf) {
      const int col = n0 + wn * (16 * NBU) + nf * 16 + lrow;
#pragma unroll
      for (int rg = 0; rg < 4; ++rg)
        C[(size_t)(row + rg) * N + col] = (OutT)acc[mf][nf][rg];
    }
  }
  (void)M;
}

// ---------------------------------------------------------------------------
// QKV epilogue (unchanged from R11).
// ---------------------------------------------------------------------------
__global__ __launch_bounds__(256) void k_qkv_epi(
    const f16_t* __restrict__ qkv, const float* __restrict__ ve,
    const float* __restrict__ qgain,
    const float* __restrict__ ctab, const float* __restrict__ stab,
    f16_t* __restrict__ qn, f16_t* __restrict__ kn, f16_t* __restrict__ vn)
{
  const int blk = blockIdx.x;           // b*2048 + t
  const int b = blk >> 11, t = blk & 2047;
  const int w = threadIdx.x >> 6, l = threadIdx.x & 63;
  const int i32 = l & 31;
  const float c = ctab[t * 32 + i32], s = stab[t * 32 + i32];
  const float EPS = 1.1920929e-07f;
  constexpr float SCALE_L2E = 0.088388347648318447f * 1.4426950408889634f;

#pragma unroll
  for (int it = 0; it < 4; ++it) {
    const int h = w + it * 4;
    const f16_t* row = qkv + (size_t)blk * 3072 + h * 128;
    float x0 = (float)row[l], x1 = (float)row[l + 64];
    float ss = x0 * x0 + x1 * x1;
#pragma unroll
    for (int off = 32; off; off >>= 1) ss += __shfl_xor(ss, off);
    const float rn = rsqrtf(ss * (1.0f / 128.0f) + EPS);
    x0 *= rn; x1 *= rn;
    const float p = __shfl_xor(x0, 32);
    float xr = (l < 32) ? (x0 * c - p * s) : (p * s + x0 * c);
    const float g = qgain[h] * SCALE_L2E;
    xr *= g; x1 *= g;
    f16_t* orow = qn + (((size_t)(b * 16 + h)) * 2048 + t) * 128;
    orow[l] = (f16_t)xr;
    orow[l + 64] = (f16_t)x1;
  }
  {
    const f16_t* row = qkv + (size_t)blk * 3072 + 2048 + w * 128;
    float x0 = (float)row[l], x1 = (float)row[l + 64];
    float ss = x0 * x0 + x1 * x1;
#pragma unroll
    for (int off = 32; off; off >>= 1) ss += __shfl_xor(ss, off);
    const float rn = rsqrtf(ss * (1.0f / 128.0f) + EPS);
    x0 *= rn; x1 *= rn;
    const float p = __shfl_xor(x0, 32);
    const float xr = (l < 32) ? (x0 * c - p * s) : (p * s + x0 * c);
    f16_t* orow = kn + (((size_t)(b * 4 + w)) * 2048 + t) * 128;
    orow[l] = (f16_t)xr;
    orow[l + 64] = (f16_t)x1;
  }
  {
    const f16_t* row = qkv + (size_t)blk * 3072 + 2560 + w * 128;
    const float* verow = ve + (size_t)blk * 512 + w * 128;
    f16_t* orow = vn + (((size_t)(b * 4 + w)) * 2048 + t) * 128;
    orow[l] = (f16_t)((float)row[l] + verow[l]);
    orow[l + 64] = (f16_t)((float)row[l + 64] + verow[l + 64]);
  }
}

// ---------------------------------------------------------------------------
// Causal GQA flash attention, fp16, KV-split.  Jobs (blockIdx.y, 48 total):
//  j<32: qt = 31-(j>>1), sp = j&1 -> split job over half the KV tiles,
//        writes unnormalized partials (po f16, pm/pl f32).
//  j>=32: qt = 47-j (0..15), single job, writes y directly.
// QBLK=64 (4 waves x 16 q-rows), KVBLK=64.  LDS: lsK [64][136], lsV^T
// [128][72] XOR-swizzled (vectorized from pre-transposed vt), lsP [16][72]
// per wave.  45KB -> 3 blocks/CU.  rsum lane-reduce deferred to end.
// ---------------------------------------------------------------------------
__global__ __launch_bounds__(256, 3) void k_attn(
    const f16_t* __restrict__ qn, const f16_t* __restrict__ kn,
    const f16_t* __restrict__ vt, f16_t* __restrict__ y,
    f16_t* __restrict__ po, float* __restrict__ pm, float* __restrict__ pl)
{
  __shared__ __align__(16) f16_t lsK[64 * 136];      // 17408 B
  __shared__ __align__(16) f16_t lsV[128 * 72];      // 18432 B
  __shared__ __align__(16) f16_t lsPb[4][16 * 72];   //  9216 B
  const int j = blockIdx.y;
  int qt, sp, tstart, tcnt;
  bool split;
  if (j < 32) {
    qt = 31 - (j >> 1); sp = j & 1; split = true;
    const int tot = qt + 1, c0 = (tot + 1) >> 1;
    tstart = sp ? c0 : 0;
    tcnt = sp ? tot - c0 : c0;
  } else {
    qt = 47 - j; sp = 0; split = false; tstart = 0; tcnt = qt + 1;
  }
  const int bh = blockIdx.x;            // 0..31
  const int b = bh >> 4, h = bh & 15, kvh = h >> 2;
  const int tid = threadIdx.x, w = tid >> 6, l = tid & 63;
  const int lrow = l & 15, lk = l >> 4;
  const int qbase = qt * 64 + w * 16;
  constexpr float NEG = -1e30f;
  f16_t* lsP = lsPb[w];

  // Q fragments (A-frag: row = lane&15, k = lk*8+j)
  const f16_t* qp = qn + ((size_t)(b * 16 + h) * 2048) * 128;
  f16x8 aQ[4];
#pragma unroll
  for (int kf = 0; kf < 4; ++kf)
    aQ[kf] = *reinterpret_cast<const f16x8*>(
        qp + (size_t)(qbase + lrow) * 128 + kf * 32 + lk * 8);

  const f16_t* kp = kn + ((size_t)(b * 4 + kvh) * 2048) * 128;
  const f16_t* vtp = vt + (size_t)(b * 4 + kvh) * 128 * 2048;

  f32x4 o[8] = {};
  float mst[4], lst[4];   // lst is a PER-LANE partial (reduced at end)
#pragma unroll
  for (int rg = 0; rg < 4; ++rg) { mst[rg] = NEG; lst[rg] = 0.f; }

  f16x8 kreg[4], vreg[4];
  auto loadKV = [&](int t0) {
#pragma unroll
    for (int it = 0; it < 4; ++it) {
      const int cch = tid + it * 256;
      kreg[it] = *reinterpret_cast<const f16x8*>(
          kp + (size_t)(t0 + (cch >> 4)) * 128 + (cch & 15) * 8);
      vreg[it] = *reinterpret_cast<const f16x8*>(
          vtp + (size_t)(cch >> 3) * 2048 + t0 + (cch & 7) * 8);
    }
  };
  loadKV(tstart * 64);

  for (int ti = 0; ti < tcnt; ++ti) {
    const int tt = tstart + ti;
    __syncthreads();  // prior tile's K/V LDS reads done before restage
#pragma unroll
    for (int it = 0; it < 4; ++it) {
      const int cch = tid + it * 256;
      const int r = cch >> 4, dg = cch & 15;
      *reinterpret_cast<f16x8*>(&lsK[r * 136 + dg * 8]) = kreg[it];
      const int d = cch >> 3, c8 = cch & 7;
      *reinterpret_cast<f16x8*>(&lsV[d * 72 + ((c8 ^ ((d >> 3) & 7)) << 3)]) = vreg[it];
    }
    if (ti + 1 < tcnt) loadKV((tt + 1) * 64);
    __syncthreads();  // staged data visible

    // S = Q K^T  (16 q-rows x 64 kv)
    f32x4 sacc[4] = {};
#pragma unroll
    for (int cf = 0; cf < 4; ++cf) {
      const int krow = cf * 16 + lrow;
#pragma unroll
      for (int kf = 0; kf < 4; ++kf) {
        const f16x8 bK = *reinterpret_cast<const f16x8*>(
            &lsK[krow * 136 + kf * 32 + lk * 8]);
        sacc[cf] = MFMA16F(aQ[kf], bK, sacc[cf]);
      }
    }

    // online softmax, log2 domain; mask only on diagonal tile
    if (tt == qt) {
#pragma unroll
      for (int rg = 0; rg < 4; ++rg) {
        const int qi = w * 16 + lk * 4 + rg;  // within-tile row
#pragma unroll
        for (int cf = 0; cf < 4; ++cf)
          if (cf * 16 + lrow > qi) sacc[cf][rg] = NEG;
      }
    }
    float pmax[4];
#pragma unroll
    for (int rg = 0; rg < 4; ++rg) {
      float mx = fmaxf(fmaxf(sacc[0][rg], sacc[1][rg]),
                       fmaxf(sacc[2][rg], sacc[3][rg]));
      mx = fmaxf(mx, __shfl_xor(mx, 1));
      mx = fmaxf(mx, __shfl_xor(mx, 2));
      mx = fmaxf(mx, __shfl_xor(mx, 4));
      mx = fmaxf(mx, __shfl_xor(mx, 8));
      pmax[rg] = mx;
    }
    const bool grow = (pmax[0] > mst[0] + 8.f) | (pmax[1] > mst[1] + 8.f) |
                      (pmax[2] > mst[2] + 8.f) | (pmax[3] > mst[3] + 8.f);
    if (__any(grow)) {
#pragma unroll
      for (int rg = 0; rg < 4; ++rg) {
        const float mnew = fmaxf(mst[rg], pmax[rg]);
        const float alpha = exp2f(mst[rg] - mnew);
        mst[rg] = mnew;
        lst[rg] *= alpha;   // per-lane partial: row-uniform scale, still exact
#pragma unroll
        for (int df = 0; df < 8; ++df) o[df][rg] *= alpha;
      }
    }
#pragma unroll
    for (int rg = 0; rg < 4; ++rg) {
      float rsum = 0.f;
#pragma unroll
      for (int cf = 0; cf < 4; ++cf) {
        const float p = exp2f(sacc[cf][rg] - mst[rg]);
        sacc[cf][rg] = p;
        rsum += p;
      }
      lst[rg] += rsum;   // no cross-lane reduce here (deferred)
    }

    // P -> per-wave LDS (A-frag layout [16][72]); same-wave write->read
#pragma unroll
    for (int cf = 0; cf < 4; ++cf)
#pragma unroll
      for (int rg = 0; rg < 4; ++rg)
        lsP[(lk * 4 + rg) * 72 + cf * 16 + lrow] = (f16_t)sacc[cf][rg];
    // PV
#pragma unroll
    for (int k2 = 0; k2 < 2; ++k2) {
      const f16x8 aP = *reinterpret_cast<const f16x8*>(
          &lsP[lrow * 72 + k2 * 32 + lk * 8]);
#pragma unroll
      for (int df = 0; df < 8; ++df) {
        const int row = df * 16 + lrow;
        const int colb = (k2 * 32 + lk * 8) ^ (((row >> 3) & 7) << 3);
        const f16x8 bV = *reinterpret_cast<const f16x8*>(&lsV[row * 72 + colb]);
        o[df] = MFMA16F(aP, bV, o[df]);
      }
    }
  }

  // deferred lane-reduce of lst (over the 16 lrow lanes)
#pragma unroll
  for (int rg = 0; rg < 4; ++rg) {
    float s = lst[rg];
    s += __shfl_xor(s, 1);
    s += __shfl_xor(s, 2);
    s += __shfl_xor(s, 4);
    s += __shfl_xor(s, 8);
    lst[rg] = s;
  }

  if (!split) {
    // normalize + write y [b][t][h*128+d]
#pragma unroll
    for (int rg = 0; rg < 4; ++rg) {
      const float inv = 1.0f / lst[rg];
      const int qi = qbase + lk * 4 + rg;
      const size_t rowoff = ((size_t)(b * 2048 + qi)) * 2048 + h * 128;
#pragma unroll
      for (int df = 0; df < 8; ++df)
        y[rowoff + df * 16 + lrow] = (f16_t)(o[df][rg] * inv);
    }
  } else {
    // write unnormalized partials; qidx = q - 1024 (qt>=16 => q in [1024,2048))
#pragma unroll
    for (int rg = 0; rg < 4; ++rg) {
      const int qi = qbase + lk * 4 + rg;
      const size_t base = (((size_t)(sp * 2 + b) * 16 + h) * 1024 + (qi - 1024));
      f16_t* prow = po + base * 128;
#pragma unroll
      for (int df = 0; df < 8; ++df)
        prow[df * 16 + lrow] = (f16_t)o[df][rg];
      if (lrow == 0) { pm[base] = mst[rg]; pl[base] = lst[rg]; }
    }
  }
}

// ---------------------------------------------------------------------------
// Combine partials for q rows [1024,2048) of each (b,h):
// y = (f1*o1 + f2*o2) / (f1*l1 + f2*l2), fi = 2^(mi - max(m1,m2)).
// grid (32 bh, 32 chunks), 256 thr: 32 rows x 8 threads (16 d each).
// ---------------------------------------------------------------------------
__global__ __launch_bounds__(256) void k_combine(
    const f16_t* __restrict__ po, const float* __restrict__ pm,
    const float* __restrict__ pl, f16_t* __restrict__ y)
{
  const int bh = blockIdx.x;            // 0..31
  const int b = bh >> 4, h = bh & 15;
  const int tid = threadIdx.x;
  const int r = blockIdx.y * 32 + (tid >> 3);   // qidx 0..1023
  const int d0 = (tid & 7) * 16;
  const size_t base1 = (((size_t)(0 * 2 + b) * 16 + h) * 1024 + r);
  const size_t base2 = (((size_t)(1 * 2 + b) * 16 + h) * 1024 + r);
  const float m1 = pm[base1], m2 = pm[base2];
  const float l1 = pl[base1], l2 = pl[base2];
  const float m = fmaxf(m1, m2);
  const float f1 = exp2f(m1 - m), f2 = exp2f(m2 - m);
  const float inv = 1.0f / (f1 * l1 + f2 * l2);
  const f16_t* o1 = po + base1 * 128 + d0;
  const f16_t* o2 = po + base2 * 128 + d0;
  f16_t* yr = y + ((size_t)(b * 2048 + 1024 + r)) * 2048 + h * 128 + d0;
#pragma unroll
  for (int v = 0; v < 2; ++v) {
    const f16x8 a = *reinterpret_cast<const f16x8*>(o1 + v * 8);
    const f16x8 c = *reinterpret_cast<const f16x8*>(o2 + v * 8);
    f16_t outv[8];
#pragma unroll
    for (int jj = 0; jj < 8; ++jj)
      outv[jj] = (f16_t)((f1 * (float)a[jj] + f2 * (float)c[jj]) * inv);
    *reinterpret_cast<f16x8*>(yr + v * 8) = *reinterpret_cast<const f16x8*>(outv);
  }
}

// ---------------------------------------------------------------------------
extern "C" void kernel_launch(void* const* d_in, const int* in_sizes, int n_in,
                              void* d_out, int out_size, void* d_ws, size_t ws_size,
                              hipStream_t stream) {
  const float* x  = (const float*)d_in[0];
  const float* ve = (const float*)d_in[1];
  const float* Wq = (const float*)d_in[2];
  const float* Wk = (const float*)d_in[3];
  const float* Wv = (const float*)d_in[4];
  const float* Wp = (const float*)d_in[5];
  const float* qg = (const float*)d_in[6];
  float* out = (float*)d_out;

  char* ws = (char*)d_ws;
  size_t off = 0;
  auto alloc = [&](size_t bytes) -> char* {
    char* p = ws + off;
    off += (bytes + 255) & ~(size_t)255;
    return p;
  };

  f16_t* xf    = (f16_t*)alloc((size_t)4096 * 2048 * 2);   // later qn
  f16_t* wqkvf = (f16_t*)alloc((size_t)3072 * 2048 * 2);   // rows Wq|Wk|Wv
  f16_t* wpf   = (f16_t*)alloc((size_t)2048 * 2048 * 2);
  f16_t* qkvf  = (f16_t*)alloc((size_t)4096 * 3072 * 2);   // GEMM out; later yb
  f16_t* kn    = (f16_t*)alloc((size_t)2 * 4 * 2048 * 128 * 2);
  f16_t* vn    = (f16_t*)alloc((size_t)2 * 4 * 2048 * 128 * 2);
  f16_t* vt    = (f16_t*)alloc((size_t)2 * 4 * 128 * 2048 * 2);
  f16_t* po    = (f16_t*)alloc((size_t)2 * 2 * 16 * 1024 * 128 * 2);
  float* pm    = (float*)alloc((size_t)2 * 2 * 16 * 1024 * 4);
  float* pl    = (float*)alloc((size_t)2 * 2 * 16 * 1024 * 4);
  float* ctab  = (float*)alloc((size_t)2048 * 32 * 4);
  float* stab  = (float*)alloc((size_t)2048 * 32 * 4);
  f16_t* qn    = xf;      // xf dead after QKV GEMM
  f16_t* yb    = qkvf;    // qkvf dead after epilogue
  (void)ws_size; (void)in_sizes; (void)n_in; (void)out_size;

  k_cast_f16<<<1024, 256, 0, stream>>>(x, xf, (long)4096 * 2048);
  k_cast_wqkv<<<1536, 256, 0, stream>>>(Wq, Wk, Wv, wqkvf);
  k_cast_f16<<<1024, 256, 0, stream>>>(Wp, wpf, (long)2048 * 2048);
  k_rope_tab<<<256, 256, 0, stream>>>(ctab, stab);

  // qkvf = x·[Wq|Wk|Wv]^T  (M=4096 N=3072 K=2048; 256x192 tiles, grid 16x16)
  k_gemmQ<3, f16_t><<<dim3(16, 16), 1024, 0, stream>>>(
      xf, wqkvf, qkvf, 4096, 3072, 2048, 2048, 2048);

  k_qkv_epi<<<4096, 256, 0, stream>>>(qkvf, ve, qg, ctab, stab, qn, kn, vn);

  k_vtrans<<<dim3(32, 8), 256, 0, stream>>>(vn, vt);

  k_attn<<<dim3(32, 48), 256, 0, stream>>>(qn, kn, vt, yb, po, pm, pl);

  k_combine<<<dim3(32, 32), 256, 0, stream>>>(po, pm, pl, yb);

  // out = y · Wp^T  (M=4096 N=2048 K=2048; 256x128 tiles, grid 16x16)
  k_gemmQ<2, float><<<dim3(16, 16), 1024, 0, stream>>>(
      yb, wpf, out, 4096, 2048, 2048, 2048, 2048);
}